// Round 3
// baseline (484.028 us; speedup 1.0000x reference)
//
#include <hip/hip_runtime.h>
#include <cstdint>

#define N 8192
#define NT 128    // 64-col tiles per row (N/64)
#define NGRP 64   // scan groups of 128 rows
typedef unsigned long long u64;
typedef unsigned int u32;

__device__ inline u64 readlane64(u64 v, int lane) {
  u32 lo = (u32)__builtin_amdgcn_readlane((int)(u32)v, lane);
  u32 hi = (u32)__builtin_amdgcn_readlane((int)(u32)(v >> 32), lane);
  return ((u64)hi << 32) | lo;
}

// ---------------------------------------------------------------------------
// K1: sort keys (descending score, stable ascending index) + init aux + pub=0
// ---------------------------------------------------------------------------
__global__ __launch_bounds__(256) void k_init(const float* __restrict__ scores,
                                              u64* __restrict__ keys,
                                              int* __restrict__ rank,
                                              int* __restrict__ cnt,
                                              float* __restrict__ prob,
                                              unsigned* __restrict__ y2m,
                                              int* __restrict__ first,
                                              u64* __restrict__ pub) {
  int i = blockIdx.x * 256 + threadIdx.x;
  if (i >= N) return;
  float sc = scores[i];
  keys[i] = ((u64)__float_as_uint(sc) << 32) | (unsigned)(0xFFFFFFFFu - (unsigned)i);
  rank[i] = 0;
  cnt[i] = 0;
  prob[i] = 0.0f;
  y2m[i] = 0u;
  first[i] = N;
  if (i < 2 * NT) pub[i] = 0ull;   // 256 publish words (2 per 64-col chunk)
}

// ---------------------------------------------------------------------------
// K2: rank by counting (rank[i] = #{j : key[j] > key[i]}) -> stable descending
// ---------------------------------------------------------------------------
__global__ __launch_bounds__(256) void k_rank(const u64* __restrict__ keys,
                                              int* __restrict__ rank) {
  __shared__ u64 tile[1024];
  int e = blockIdx.x * 256 + threadIdx.x;
  int j0 = blockIdx.y * 1024;
  for (int t = threadIdx.x; t < 1024; t += 256) tile[t] = keys[j0 + t];
  __syncthreads();
  u64 ke = keys[e];
  int c = 0;
#pragma unroll 8
  for (int k = 0; k < 1024; ++k) c += (tile[k] > ke) ? 1 : 0;
  atomicAdd(&rank[e], c);
}

// ---------------------------------------------------------------------------
// K3: scatter into sorted SoA (clipped coords, score, area)
// ---------------------------------------------------------------------------
__global__ __launch_bounds__(256) void k_scatter(const float* __restrict__ boxes,
                                                 const float* __restrict__ scores,
                                                 const int* __restrict__ rank,
                                                 float* __restrict__ bx1s, float* __restrict__ by1s,
                                                 float* __restrict__ bx2s, float* __restrict__ by2s,
                                                 float* __restrict__ ss, float* __restrict__ areas) {
#pragma clang fp contract(off)
  int i = blockIdx.x * 256 + threadIdx.x;
  if (i >= N) return;
  int r = rank[i];
  float x1 = fminf(fmaxf(boxes[i * 4 + 0], 0.0f), 1920.0f);
  float y1 = fminf(fmaxf(boxes[i * 4 + 1], 0.0f), 1080.0f);
  float x2 = fminf(fmaxf(boxes[i * 4 + 2], 0.0f), 1920.0f);
  float y2 = fminf(fmaxf(boxes[i * 4 + 3], 0.0f), 1080.0f);
  bx1s[r] = x1; by1s[r] = y1; bx2s[r] = x2; by2s[r] = y2;
  ss[r] = scores[i];
  areas[r] = (x2 - x1 + 1.0f) * (y2 - y1 + 1.0f);
}

// ---------------------------------------------------------------------------
// K4: adjacency, TILED layout: mtile[(gy*128+gx)*64 + lane] = row (64gy+lane)'s
// bits over cols [64gx, 64gx+64). Stores now coalesced (512B/wave, was 1KB
// lane stride). fp contract OFF to match numpy bit-for-bit; matrix is
// float-exact symmetric (k_scan/k_cluster rely on column j == row j).
// ---------------------------------------------------------------------------
__global__ __launch_bounds__(64) void k_adj(const float* __restrict__ bx1s, const float* __restrict__ by1s,
                                            const float* __restrict__ bx2s, const float* __restrict__ by2s,
                                            const float* __restrict__ areas,
                                            u64* __restrict__ mtile) {
#pragma clang fp contract(off)
  __shared__ float jx1[64], jy1[64], jx2[64], jy2[64], ja[64];
  int l = threadIdx.x;
  int j = blockIdx.x * 64 + l;
  jx1[l] = bx1s[j]; jy1[l] = by1s[j]; jx2[l] = bx2s[j]; jy2[l] = by2s[j]; ja[l] = areas[j];
  __syncthreads();
  int i = blockIdx.y * 64 + l;
  float x1 = bx1s[i], y1 = by1s[i], x2 = bx2s[i], y2 = by2s[i], ai = areas[i];
  u64 bits = 0;
#pragma unroll 4
  for (int jj = 0; jj < 64; ++jj) {
    float ix1 = fmaxf(x1, jx1[jj]);
    float iy1 = fmaxf(y1, jy1[jj]);
    float ix2 = fminf(x2, jx2[jj]);
    float iy2 = fminf(y2, jy2[jj]);
    float iw = fmaxf(ix2 - ix1 + 1.0f, 0.0f);
    float ih = fmaxf(iy2 - iy1 + 1.0f, 0.0f);
    float inter = iw * ih;
    float uni = (ai + ja[jj]) - inter;
    float iou = inter / uni;
    bits |= ((u64)(iou > 0.5f)) << jj;
  }
  mtile[((size_t)blockIdx.y * NT + blockIdx.x) * 64 + l] = bits;
}

// ---------------------------------------------------------------------------
// K5: head discovery, decoupled lookback. 64 blocks (1 wave each), block g
// owns rows [128g, 128g+128) (row-tile indices 2g, 2g+1).
//  - loads its tile strip in parallel with all other blocks (chunked dbuf)
//  - for each previous 64-col chunk k: poll pub[2k],pub[2k+1] (self-flagged
//    words: (bits<<1)|1, agent scope), acc |= ballot(row & heads != 0)
//  - in-group greedy resolve via diagonal tiles + readlane chains
//  - publish own head bits. head[i] = no earlier head adjacent -> exact
//    greedy-NMS head set; cluster assignment is then fully parallel (K6).
// ---------------------------------------------------------------------------
__global__ __launch_bounds__(64, 1) void k_scan(const u64* __restrict__ mtile,
                                                u64* __restrict__ pub) {
  const int g = blockIdx.x;
  const int r = threadIdx.x;
  const int ra = 2 * g, rb = 2 * g + 1;

  u64 dAA = mtile[((size_t)ra * NT + ra) * 64 + r];
  u64 dAB = mtile[((size_t)ra * NT + rb) * 64 + r];
  u64 dBB = mtile[((size_t)rb * NT + rb) * 64 + r];

  u64 acc0 = 0, acc1 = 0;       // removed-by-previous-heads bits (ballot space)
  const int kend = 2 * g;       // previous 64-col chunks
  const int CH = 16;
  u64 cA[CH], cB[CH], nA[CH], nB[CH];
#pragma unroll
  for (int t = 0; t < CH; ++t) {        // chunk 0 (always valid addresses)
    cA[t] = mtile[((size_t)ra * NT + t) * 64 + r];
    cB[t] = mtile[((size_t)rb * NT + t) * 64 + r];
  }
  for (int base = 0; base < kend; base += CH) {
#pragma unroll
    for (int t = 0; t < CH; ++t) {      // prefetch next chunk (clamped, valid)
      int k = base + CH + t; if (k > NT - 1) k = NT - 1;
      nA[t] = mtile[((size_t)ra * NT + k) * 64 + r];
      nB[t] = mtile[((size_t)rb * NT + k) * 64 + r];
    }
#pragma unroll
    for (int t = 0; t < CH; ++t) {
      int k = base + t;
      if (k < kend) {
        u64 plo, phi;
        do {
          plo = __hip_atomic_load(&pub[2 * k], __ATOMIC_RELAXED, __HIP_MEMORY_SCOPE_AGENT);
          phi = __hip_atomic_load(&pub[2 * k + 1], __ATOMIC_RELAXED, __HIP_MEMORY_SCOPE_AGENT);
        } while (plo == 0ull || phi == 0ull);
        u64 h = (plo >> 1) | ((phi >> 1) << 32);
        acc0 |= __ballot((cA[t] & h) != 0ull);
        acc1 |= __ballot((cB[t] & h) != 0ull);
      }
    }
#pragma unroll
    for (int t = 0; t < CH; ++t) { cA[t] = nA[t]; cB[t] = nB[t]; }
  }

  // in-group greedy resolve (uniform scalar loop; self-bit adj[i][i]=1 clears i)
  u64 todo0 = ~acc0, todo1 = ~acc1;
  u64 hm0 = 0, hm1 = 0;
  while (todo0) {
    int i = __builtin_ctzll(todo0);
    hm0 |= 1ull << i;
    todo0 &= ~readlane64(dAA, i);
    todo1 &= ~readlane64(dAB, i);
  }
  while (todo1) {
    int i = __builtin_ctzll(todo1);
    hm1 |= 1ull << i;
    todo1 &= ~readlane64(dBB, i);
  }
  if (r == 0) {
    __hip_atomic_store(&pub[4 * g + 0], ((hm0 & 0xffffffffull) << 1) | 1ull, __ATOMIC_RELEASE, __HIP_MEMORY_SCOPE_AGENT);
    __hip_atomic_store(&pub[4 * g + 1], ((hm0 >> 32) << 1) | 1ull, __ATOMIC_RELEASE, __HIP_MEMORY_SCOPE_AGENT);
    __hip_atomic_store(&pub[4 * g + 2], ((hm1 & 0xffffffffull) << 1) | 1ull, __ATOMIC_RELEASE, __HIP_MEMORY_SCOPE_AGENT);
    __hip_atomic_store(&pub[4 * g + 3], ((hm1 >> 32) << 1) | 1ull, __ATOMIC_RELEASE, __HIP_MEMORY_SCOPE_AGENT);
  }
}

// ---------------------------------------------------------------------------
// K6: parallel cluster assignment + segment atomics. Block per 64-row group;
// wave w scans col-chunks [32w,32w+32) coalesced; cluster[j] = first head
// adjacent to j (symmetry: row j == column j). Every j hits (itself if head).
// ---------------------------------------------------------------------------
__global__ __launch_bounds__(256) void k_cluster(const u64* __restrict__ mtile,
                                                 const u64* __restrict__ pub,
                                                 const float* __restrict__ ss,
                                                 const float* __restrict__ by2s,
                                                 int* __restrict__ cluster,
                                                 int* __restrict__ cnt,
                                                 float* __restrict__ prob,
                                                 unsigned* __restrict__ y2m) {
  __shared__ u64 hlds[NT];
  __shared__ int red[4][64];
  int gy = blockIdx.x;
  if (threadIdx.x < NT) {
    u64 plo = pub[2 * threadIdx.x], phi = pub[2 * threadIdx.x + 1];
    hlds[threadIdx.x] = (plo >> 1) | ((phi >> 1) << 32);
  }
  __syncthreads();
  int w = threadIdx.x >> 6, r = threadIdx.x & 63;
  int best = 0x7fffffff;
  for (int kk = 0; kk < 32; ++kk) {
    int k = 32 * w + kk;
    u64 v = mtile[((size_t)gy * NT + k) * 64 + r] & hlds[k];
    if (v && best == 0x7fffffff) best = k * 64 + __builtin_ctzll(v);
  }
  red[w][r] = best;
  __syncthreads();
  if (w == 0) {
    int b = min(min(red[0][r], red[1][r]), min(red[2][r], red[3][r]));
    int j = gy * 64 + r;
    cluster[j] = b;
    atomicAdd(&cnt[b], 1);
    atomicAdd(&prob[b], ss[j]);
    atomicMax(&y2m[b], __float_as_uint(by2s[j]));
  }
}

// ---------------------------------------------------------------------------
// K7: first index achieving the cluster max y2
// ---------------------------------------------------------------------------
__global__ __launch_bounds__(256) void k_first(const int* __restrict__ cluster,
                                               const float* __restrict__ by2s,
                                               const unsigned* __restrict__ y2m,
                                               int* __restrict__ first) {
  int j = blockIdx.x * 256 + threadIdx.x;
  if (j >= N) return;
  int c = cluster[j];
  if (by2s[j] >= __uint_as_float(y2m[c])) atomicMin(&first[c], j);
}

// ---------------------------------------------------------------------------
// K8: outputs. out[j][0..4] then keep[j] appended (floats 0/1).
// ---------------------------------------------------------------------------
__global__ __launch_bounds__(256) void k_out(const int* __restrict__ cluster,
                                             const float* __restrict__ bx1s, const float* __restrict__ by1s,
                                             const float* __restrict__ bx2s, const float* __restrict__ by2s,
                                             const int* __restrict__ cnt,
                                             const float* __restrict__ prob,
                                             const int* __restrict__ first,
                                             const int* __restrict__ num_models,
                                             float* __restrict__ out) {
  int j = blockIdx.x * 256 + threadIdx.x;
  if (j >= N) return;
  int c = cluster[j];
  int nm = num_models[0];
  bool valid = (float)cnt[c] >= (float)nm / 3.0f;
  bool pick = (first[c] == j);
  bool keep = pick && valid;
  float o0 = 0.f, o1 = 0.f, o2 = 0.f, o3 = 0.f, o4 = 0.f;
  if (keep) {
    o0 = bx1s[j]; o1 = by1s[j]; o2 = bx2s[j]; o3 = by2s[j];
    o4 = prob[c] / (float)nm;
  }
  out[j * 5 + 0] = o0;
  out[j * 5 + 1] = o1;
  out[j * 5 + 2] = o2;
  out[j * 5 + 3] = o3;
  out[j * 5 + 4] = o4;
  out[N * 5 + j] = keep ? 1.0f : 0.0f;
}

// ---------------------------------------------------------------------------
extern "C" void kernel_launch(void* const* d_in, const int* in_sizes, int n_in,
                              void* d_out, int out_size, void* d_ws, size_t ws_size,
                              hipStream_t stream) {
  const float* boxes = (const float*)d_in[0];
  const float* scores = (const float*)d_in[1];
  const int* num_models = (const int*)d_in[2];
  float* out = (float*)d_out;

  char* p = (char*)d_ws;
  auto take = [&](size_t bytes) {
    char* r = p;
    p += (bytes + 255) & ~(size_t)255;
    return r;
  };
  u64* keys   = (u64*)take((size_t)N * 8);
  int* rank   = (int*)take((size_t)N * 4);
  float* bx1s = (float*)take((size_t)N * 4);
  float* by1s = (float*)take((size_t)N * 4);
  float* bx2s = (float*)take((size_t)N * 4);
  float* by2s = (float*)take((size_t)N * 4);
  float* ss   = (float*)take((size_t)N * 4);
  float* areas= (float*)take((size_t)N * 4);
  int* cluster= (int*)take((size_t)N * 4);
  int* cnt    = (int*)take((size_t)N * 4);
  float* prob = (float*)take((size_t)N * 4);
  unsigned* y2m = (unsigned*)take((size_t)N * 4);
  int* first  = (int*)take((size_t)N * 4);
  u64* pub    = (u64*)take((size_t)2 * NT * 8);      // 256 publish words
  u64* mtile  = (u64*)take((size_t)NT * NT * 64 * 8); // 8 MiB tiled adjacency

  k_init<<<N / 256, 256, 0, stream>>>(scores, keys, rank, cnt, prob, y2m, first, pub);
  k_rank<<<dim3(N / 256, 8), 256, 0, stream>>>(keys, rank);
  k_scatter<<<N / 256, 256, 0, stream>>>(boxes, scores, rank, bx1s, by1s, bx2s, by2s, ss, areas);
  k_adj<<<dim3(NT, NT), 64, 0, stream>>>(bx1s, by1s, bx2s, by2s, areas, mtile);
  k_scan<<<NGRP, 64, 0, stream>>>(mtile, pub);
  k_cluster<<<N / 64, 256, 0, stream>>>(mtile, pub, ss, by2s, cluster, cnt, prob, y2m);
  k_first<<<N / 256, 256, 0, stream>>>(cluster, by2s, y2m, first);
  k_out<<<N / 256, 256, 0, stream>>>(cluster, bx1s, by1s, bx2s, by2s, cnt, prob, first, num_models, out);
}

// Round 4
// 417.101 us; speedup vs baseline: 1.1605x; 1.1605x over previous
//
#include <hip/hip_runtime.h>
#include <cstdint>

#define N 8192
#define NT 128    // 64-col tiles per row (N/64)
#define NGRP 64   // scan groups of 128 rows
typedef unsigned long long u64;
typedef unsigned int u32;

__device__ inline u64 readlane64(u64 v, int lane) {
  u32 lo = (u32)__builtin_amdgcn_readlane((int)(u32)v, lane);
  u32 hi = (u32)__builtin_amdgcn_readlane((int)(u32)(v >> 32), lane);
  return ((u64)hi << 32) | lo;
}

// ---------------------------------------------------------------------------
// K1: sort keys (descending score, stable ascending index) + init aux + pub=0
// ---------------------------------------------------------------------------
__global__ __launch_bounds__(256) void k_init(const float* __restrict__ scores,
                                              u64* __restrict__ keys,
                                              int* __restrict__ rank,
                                              int* __restrict__ cnt,
                                              float* __restrict__ prob,
                                              unsigned* __restrict__ y2m,
                                              int* __restrict__ first,
                                              u64* __restrict__ pub) {
  int i = blockIdx.x * 256 + threadIdx.x;
  if (i >= N) return;
  float sc = scores[i];
  keys[i] = ((u64)__float_as_uint(sc) << 32) | (unsigned)(0xFFFFFFFFu - (unsigned)i);
  rank[i] = 0;
  cnt[i] = 0;
  prob[i] = 0.0f;
  y2m[i] = 0u;
  first[i] = N;
  if (i < 2 * NT) pub[i] = 0ull;   // 256 publish words (2 per 64-col chunk)
}

// ---------------------------------------------------------------------------
// K2: rank by counting (rank[i] = #{j : key[j] > key[i]}) -> stable descending
// ---------------------------------------------------------------------------
__global__ __launch_bounds__(256) void k_rank(const u64* __restrict__ keys,
                                              int* __restrict__ rank) {
  __shared__ u64 tile[1024];
  int e = blockIdx.x * 256 + threadIdx.x;
  int j0 = blockIdx.y * 1024;
  for (int t = threadIdx.x; t < 1024; t += 256) tile[t] = keys[j0 + t];
  __syncthreads();
  u64 ke = keys[e];
  int c = 0;
#pragma unroll 8
  for (int k = 0; k < 1024; ++k) c += (tile[k] > ke) ? 1 : 0;
  atomicAdd(&rank[e], c);
}

// ---------------------------------------------------------------------------
// K3: scatter into sorted SoA (clipped coords, score, area)
// ---------------------------------------------------------------------------
__global__ __launch_bounds__(256) void k_scatter(const float* __restrict__ boxes,
                                                 const float* __restrict__ scores,
                                                 const int* __restrict__ rank,
                                                 float* __restrict__ bx1s, float* __restrict__ by1s,
                                                 float* __restrict__ bx2s, float* __restrict__ by2s,
                                                 float* __restrict__ ss, float* __restrict__ areas) {
#pragma clang fp contract(off)
  int i = blockIdx.x * 256 + threadIdx.x;
  if (i >= N) return;
  int r = rank[i];
  float x1 = fminf(fmaxf(boxes[i * 4 + 0], 0.0f), 1920.0f);
  float y1 = fminf(fmaxf(boxes[i * 4 + 1], 0.0f), 1080.0f);
  float x2 = fminf(fmaxf(boxes[i * 4 + 2], 0.0f), 1920.0f);
  float y2 = fminf(fmaxf(boxes[i * 4 + 3], 0.0f), 1080.0f);
  bx1s[r] = x1; by1s[r] = y1; bx2s[r] = x2; by2s[r] = y2;
  ss[r] = scores[i];
  areas[r] = (x2 - x1 + 1.0f) * (y2 - y1 + 1.0f);
}

// ---------------------------------------------------------------------------
// K4: adjacency, TILED layout: mtile[(gy*128+gx)*64 + lane] = row (64gy+lane)'s
// bits over cols [64gx, 64gx+64). fp contract OFF to match numpy bit-for-bit;
// exact IEEE divide (no fast-math) so the iou>0.5 comparison cannot flip vs
// the reference. Matrix is float-exact symmetric (k_scan/k_cluster rely on it).
// ---------------------------------------------------------------------------
__global__ __launch_bounds__(64) void k_adj(const float* __restrict__ bx1s, const float* __restrict__ by1s,
                                            const float* __restrict__ bx2s, const float* __restrict__ by2s,
                                            const float* __restrict__ areas,
                                            u64* __restrict__ mtile) {
#pragma clang fp contract(off)
  __shared__ float jx1[64], jy1[64], jx2[64], jy2[64], ja[64];
  int l = threadIdx.x;
  int j = blockIdx.x * 64 + l;
  jx1[l] = bx1s[j]; jy1[l] = by1s[j]; jx2[l] = bx2s[j]; jy2[l] = by2s[j]; ja[l] = areas[j];
  __syncthreads();
  int i = blockIdx.y * 64 + l;
  float x1 = bx1s[i], y1 = by1s[i], x2 = bx2s[i], y2 = by2s[i], ai = areas[i];
  u64 bits = 0;
#pragma unroll 4
  for (int jj = 0; jj < 64; ++jj) {
    float ix1 = fmaxf(x1, jx1[jj]);
    float iy1 = fmaxf(y1, jy1[jj]);
    float ix2 = fminf(x2, jx2[jj]);
    float iy2 = fminf(y2, jy2[jj]);
    float iw = fmaxf(ix2 - ix1 + 1.0f, 0.0f);
    float ih = fmaxf(iy2 - iy1 + 1.0f, 0.0f);
    float inter = iw * ih;
    float uni = (ai + ja[jj]) - inter;
    float iou = inter / uni;
    bits |= ((u64)(iou > 0.5f)) << jj;
  }
  mtile[((size_t)blockIdx.y * NT + blockIdx.x) * 64 + l] = bits;
}

// ---------------------------------------------------------------------------
// K5: head discovery, decoupled lookback — fixed polling protocol.
//  - XCD swizzle: logical group g = ((b&7)<<3)|(b>>3) so consecutive logical
//    groups share an XCD L2 (blockIdx%8 heuristic; speed only).
//  - batched window poll: ONE 32-lane vector atomic load covers 8 chunks'
//    pub words; targeted 2-lane spin (+s_sleep) only for unready chunks.
//    (Round-3 bug: 64-lane same-address spin -> serialized LLC hammering.)
//  - pub words self-flagged: (bits<<1)|1, relaxed atomics (data == flag).
// ---------------------------------------------------------------------------
__global__ __launch_bounds__(64, 1) void k_scan(const u64* __restrict__ mtile,
                                                u64* __restrict__ pub) {
  const int b = blockIdx.x;
  const int g = ((b & 7) << 3) | (b >> 3);
  const int r = threadIdx.x;
  const int ra = 2 * g, rb = 2 * g + 1;

  u64 dAA = mtile[((size_t)ra * NT + ra) * 64 + r];
  u64 dAB = mtile[((size_t)ra * NT + rb) * 64 + r];
  u64 dBB = mtile[((size_t)rb * NT + rb) * 64 + r];

  u64 acc0 = 0, acc1 = 0;       // removed-by-previous-heads bits (ballot space)
  const int kend = 2 * g;       // previous 64-col chunks
  const int CH = 8;

  for (int base = 0; base < kend; base += CH) {
    u64 tA[CH], tB[CH];
#pragma unroll
    for (int t = 0; t < CH; ++t) {          // window tile loads (clamped, valid)
      int k = base + t; if (k >= kend) k = kend - 1;
      tA[t] = mtile[((size_t)ra * NT + k) * 64 + r];
      tB[t] = mtile[((size_t)rb * NT + k) * 64 + r];
    }
    // batch-poll this window's pub words: lanes 0..15 -> pub[2*base .. +15]
    u64 pv = 0;
    if (r < 2 * CH)
      pv = __hip_atomic_load(&pub[2 * base + r], __ATOMIC_RELAXED, __HIP_MEMORY_SCOPE_AGENT);
#pragma unroll
    for (int t = 0; t < CH; ++t) {
      int k = base + t;
      if (k >= kend) break;                  // uniform
      u64 plo = readlane64(pv, 2 * t);
      u64 phi = readlane64(pv, 2 * t + 1);
      if (((plo & phi) & 1ull) == 0ull) {    // uniform: not yet published
        u64 v = 0;
        for (;;) {
          if (r < 2)
            v = __hip_atomic_load(&pub[2 * k + r], __ATOMIC_RELAXED, __HIP_MEMORY_SCOPE_AGENT);
          if ((__ballot((v & 1ull) != 0ull) & 3ull) == 3ull) break;
          __builtin_amdgcn_s_sleep(1);
        }
        plo = readlane64(v, 0);
        phi = readlane64(v, 1);
      }
      u64 h = (plo >> 1) | ((phi >> 1) << 32);
      acc0 |= __ballot((tA[t] & h) != 0ull);
      acc1 |= __ballot((tB[t] & h) != 0ull);
    }
  }

  // in-group greedy resolve (uniform scalar loop; self-bit adj[i][i]=1 clears i)
  u64 todo0 = ~acc0, todo1 = ~acc1;
  u64 hm0 = 0, hm1 = 0;
  while (todo0) {
    int i = __builtin_ctzll(todo0);
    hm0 |= 1ull << i;
    todo0 &= ~readlane64(dAA, i);
    todo1 &= ~readlane64(dAB, i);
  }
  while (todo1) {
    int i = __builtin_ctzll(todo1);
    hm1 |= 1ull << i;
    todo1 &= ~readlane64(dBB, i);
  }
  // publish: 4 words from 4 lanes, one vector store
  u64 w = (r == 0) ? (((hm0 & 0xffffffffull) << 1) | 1ull)
        : (r == 1) ? (((hm0 >> 32) << 1) | 1ull)
        : (r == 2) ? (((hm1 & 0xffffffffull) << 1) | 1ull)
                   : (((hm1 >> 32) << 1) | 1ull);
  if (r < 4)
    __hip_atomic_store(&pub[4 * g + r], w, __ATOMIC_RELAXED, __HIP_MEMORY_SCOPE_AGENT);
}

// ---------------------------------------------------------------------------
// K6: parallel cluster assignment + segment atomics. Block per 64-row group;
// wave w scans col-chunks [32w,32w+32) coalesced; cluster[j] = first head
// adjacent to j (symmetry: row j == column j). Every j hits (itself if head).
// ---------------------------------------------------------------------------
__global__ __launch_bounds__(256) void k_cluster(const u64* __restrict__ mtile,
                                                 const u64* __restrict__ pub,
                                                 const float* __restrict__ ss,
                                                 const float* __restrict__ by2s,
                                                 int* __restrict__ cluster,
                                                 int* __restrict__ cnt,
                                                 float* __restrict__ prob,
                                                 unsigned* __restrict__ y2m) {
  __shared__ u64 hlds[NT];
  __shared__ int red[4][64];
  int gy = blockIdx.x;
  if (threadIdx.x < NT) {
    u64 plo = pub[2 * threadIdx.x], phi = pub[2 * threadIdx.x + 1];
    hlds[threadIdx.x] = (plo >> 1) | ((phi >> 1) << 32);
  }
  __syncthreads();
  int w = threadIdx.x >> 6, r = threadIdx.x & 63;
  int best = 0x7fffffff;
  for (int kk = 0; kk < 32; ++kk) {
    int k = 32 * w + kk;
    u64 v = mtile[((size_t)gy * NT + k) * 64 + r] & hlds[k];
    if (v && best == 0x7fffffff) best = k * 64 + __builtin_ctzll(v);
  }
  red[w][r] = best;
  __syncthreads();
  if (w == 0) {
    int b = min(min(red[0][r], red[1][r]), min(red[2][r], red[3][r]));
    int j = gy * 64 + r;
    cluster[j] = b;
    atomicAdd(&cnt[b], 1);
    atomicAdd(&prob[b], ss[j]);
    atomicMax(&y2m[b], __float_as_uint(by2s[j]));
  }
}

// ---------------------------------------------------------------------------
// K7: first index achieving the cluster max y2
// ---------------------------------------------------------------------------
__global__ __launch_bounds__(256) void k_first(const int* __restrict__ cluster,
                                               const float* __restrict__ by2s,
                                               const unsigned* __restrict__ y2m,
                                               int* __restrict__ first) {
  int j = blockIdx.x * 256 + threadIdx.x;
  if (j >= N) return;
  int c = cluster[j];
  if (by2s[j] >= __uint_as_float(y2m[c])) atomicMin(&first[c], j);
}

// ---------------------------------------------------------------------------
// K8: outputs. out[j][0..4] then keep[j] appended (floats 0/1).
// ---------------------------------------------------------------------------
__global__ __launch_bounds__(256) void k_out(const int* __restrict__ cluster,
                                             const float* __restrict__ bx1s, const float* __restrict__ by1s,
                                             const float* __restrict__ bx2s, const float* __restrict__ by2s,
                                             const int* __restrict__ cnt,
                                             const float* __restrict__ prob,
                                             const int* __restrict__ first,
                                             const int* __restrict__ num_models,
                                             float* __restrict__ out) {
  int j = blockIdx.x * 256 + threadIdx.x;
  if (j >= N) return;
  int c = cluster[j];
  int nm = num_models[0];
  bool valid = (float)cnt[c] >= (float)nm / 3.0f;
  bool pick = (first[c] == j);
  bool keep = pick && valid;
  float o0 = 0.f, o1 = 0.f, o2 = 0.f, o3 = 0.f, o4 = 0.f;
  if (keep) {
    o0 = bx1s[j]; o1 = by1s[j]; o2 = bx2s[j]; o3 = by2s[j];
    o4 = prob[c] / (float)nm;
  }
  out[j * 5 + 0] = o0;
  out[j * 5 + 1] = o1;
  out[j * 5 + 2] = o2;
  out[j * 5 + 3] = o3;
  out[j * 5 + 4] = o4;
  out[N * 5 + j] = keep ? 1.0f : 0.0f;
}

// ---------------------------------------------------------------------------
extern "C" void kernel_launch(void* const* d_in, const int* in_sizes, int n_in,
                              void* d_out, int out_size, void* d_ws, size_t ws_size,
                              hipStream_t stream) {
  const float* boxes = (const float*)d_in[0];
  const float* scores = (const float*)d_in[1];
  const int* num_models = (const int*)d_in[2];
  float* out = (float*)d_out;

  char* p = (char*)d_ws;
  auto take = [&](size_t bytes) {
    char* r = p;
    p += (bytes + 255) & ~(size_t)255;
    return r;
  };
  u64* keys   = (u64*)take((size_t)N * 8);
  int* rank   = (int*)take((size_t)N * 4);
  float* bx1s = (float*)take((size_t)N * 4);
  float* by1s = (float*)take((size_t)N * 4);
  float* bx2s = (float*)take((size_t)N * 4);
  float* by2s = (float*)take((size_t)N * 4);
  float* ss   = (float*)take((size_t)N * 4);
  float* areas= (float*)take((size_t)N * 4);
  int* cluster= (int*)take((size_t)N * 4);
  int* cnt    = (int*)take((size_t)N * 4);
  float* prob = (float*)take((size_t)N * 4);
  unsigned* y2m = (unsigned*)take((size_t)N * 4);
  int* first  = (int*)take((size_t)N * 4);
  u64* pub    = (u64*)take((size_t)2 * NT * 8);      // 256 publish words
  u64* mtile  = (u64*)take((size_t)NT * NT * 64 * 8); // 8 MiB tiled adjacency

  k_init<<<N / 256, 256, 0, stream>>>(scores, keys, rank, cnt, prob, y2m, first, pub);
  k_rank<<<dim3(N / 256, 8), 256, 0, stream>>>(keys, rank);
  k_scatter<<<N / 256, 256, 0, stream>>>(boxes, scores, rank, bx1s, by1s, bx2s, by2s, ss, areas);
  k_adj<<<dim3(NT, NT), 64, 0, stream>>>(bx1s, by1s, bx2s, by2s, areas, mtile);
  k_scan<<<NGRP, 64, 0, stream>>>(mtile, pub);
  k_cluster<<<N / 64, 256, 0, stream>>>(mtile, pub, ss, by2s, cluster, cnt, prob, y2m);
  k_first<<<N / 256, 256, 0, stream>>>(cluster, by2s, y2m, first);
  k_out<<<N / 256, 256, 0, stream>>>(cluster, bx1s, by1s, bx2s, by2s, cnt, prob, first, num_models, out);
}

// Round 5
// 413.294 us; speedup vs baseline: 1.1711x; 1.0092x over previous
//
#include <hip/hip_runtime.h>
#include <cstdint>

#define N 8192
#define NT 128    // 64-col tiles per row (N/64)
#define NGRP 64   // scan groups of 128 rows
typedef unsigned long long u64;
typedef unsigned int u32;

typedef __attribute__((address_space(1))) const void gas_void;
typedef __attribute__((address_space(3))) void las_void;

__device__ inline u64 readlane64(u64 v, int lane) {
  u32 lo = (u32)__builtin_amdgcn_readlane((int)(u32)v, lane);
  u32 hi = (u32)__builtin_amdgcn_readlane((int)(u32)(v >> 32), lane);
  return ((u64)hi << 32) | lo;
}

// ---------------------------------------------------------------------------
// K1: sort keys (descending score, stable ascending index) + init aux + pub=0
// ---------------------------------------------------------------------------
__global__ __launch_bounds__(256) void k_init(const float* __restrict__ scores,
                                              u64* __restrict__ keys,
                                              int* __restrict__ rank,
                                              int* __restrict__ cnt,
                                              float* __restrict__ prob,
                                              unsigned* __restrict__ y2m,
                                              int* __restrict__ first,
                                              u64* __restrict__ pub) {
  int i = blockIdx.x * 256 + threadIdx.x;
  if (i >= N) return;
  float sc = scores[i];
  keys[i] = ((u64)__float_as_uint(sc) << 32) | (unsigned)(0xFFFFFFFFu - (unsigned)i);
  rank[i] = 0;
  cnt[i] = 0;
  prob[i] = 0.0f;
  y2m[i] = 0u;
  first[i] = N;
  if (i < 2 * NT) pub[i] = 0ull;   // 256 publish words (2 per 64-col chunk)
}

// ---------------------------------------------------------------------------
// K2: rank by counting (rank[i] = #{j : key[j] > key[i]}) -> stable descending
// ---------------------------------------------------------------------------
__global__ __launch_bounds__(256) void k_rank(const u64* __restrict__ keys,
                                              int* __restrict__ rank) {
  __shared__ u64 tile[1024];
  int e = blockIdx.x * 256 + threadIdx.x;
  int j0 = blockIdx.y * 1024;
  for (int t = threadIdx.x; t < 1024; t += 256) tile[t] = keys[j0 + t];
  __syncthreads();
  u64 ke = keys[e];
  int c = 0;
#pragma unroll 8
  for (int k = 0; k < 1024; ++k) c += (tile[k] > ke) ? 1 : 0;
  atomicAdd(&rank[e], c);
}

// ---------------------------------------------------------------------------
// K3: scatter into sorted SoA (clipped coords, score, area)
// ---------------------------------------------------------------------------
__global__ __launch_bounds__(256) void k_scatter(const float* __restrict__ boxes,
                                                 const float* __restrict__ scores,
                                                 const int* __restrict__ rank,
                                                 float* __restrict__ bx1s, float* __restrict__ by1s,
                                                 float* __restrict__ bx2s, float* __restrict__ by2s,
                                                 float* __restrict__ ss, float* __restrict__ areas) {
#pragma clang fp contract(off)
  int i = blockIdx.x * 256 + threadIdx.x;
  if (i >= N) return;
  int r = rank[i];
  float x1 = fminf(fmaxf(boxes[i * 4 + 0], 0.0f), 1920.0f);
  float y1 = fminf(fmaxf(boxes[i * 4 + 1], 0.0f), 1080.0f);
  float x2 = fminf(fmaxf(boxes[i * 4 + 2], 0.0f), 1920.0f);
  float y2 = fminf(fmaxf(boxes[i * 4 + 3], 0.0f), 1080.0f);
  bx1s[r] = x1; by1s[r] = y1; bx2s[r] = x2; by2s[r] = y2;
  ss[r] = scores[i];
  areas[r] = (x2 - x1 + 1.0f) * (y2 - y1 + 1.0f);
}

// ---------------------------------------------------------------------------
// K4: adjacency, TILED layout: mtile[(gy*128+gx)*64 + lane] = row (64gy+lane)'s
// bits over cols [64gx, 64gx+64). fp contract OFF to match numpy bit-for-bit;
// exact IEEE divide so the iou>0.5 compare cannot flip vs the reference.
// Matrix is float-exact symmetric (k_scan/k_cluster rely on column j == row j).
// ---------------------------------------------------------------------------
__global__ __launch_bounds__(64) void k_adj(const float* __restrict__ bx1s, const float* __restrict__ by1s,
                                            const float* __restrict__ bx2s, const float* __restrict__ by2s,
                                            const float* __restrict__ areas,
                                            u64* __restrict__ mtile) {
#pragma clang fp contract(off)
  __shared__ float jx1[64], jy1[64], jx2[64], jy2[64], ja[64];
  int l = threadIdx.x;
  int j = blockIdx.x * 64 + l;
  jx1[l] = bx1s[j]; jy1[l] = by1s[j]; jx2[l] = bx2s[j]; jy2[l] = by2s[j]; ja[l] = areas[j];
  __syncthreads();
  int i = blockIdx.y * 64 + l;
  float x1 = bx1s[i], y1 = by1s[i], x2 = bx2s[i], y2 = by2s[i], ai = areas[i];
  u64 bits = 0;
#pragma unroll 4
  for (int jj = 0; jj < 64; ++jj) {
    float ix1 = fmaxf(x1, jx1[jj]);
    float iy1 = fmaxf(y1, jy1[jj]);
    float ix2 = fminf(x2, jx2[jj]);
    float iy2 = fminf(y2, jy2[jj]);
    float iw = fmaxf(ix2 - ix1 + 1.0f, 0.0f);
    float ih = fmaxf(iy2 - iy1 + 1.0f, 0.0f);
    float inter = iw * ih;
    float uni = (ai + ja[jj]) - inter;
    float iou = inter / uni;
    bits |= ((u64)(iou > 0.5f)) << jj;
  }
  mtile[((size_t)blockIdx.y * NT + blockIdx.x) * 64 + l] = bits;
}

// ---------------------------------------------------------------------------
// K5: head discovery, decoupled lookback. Per 8-chunk window:
//   1) async global_load_lds prefetch of the window's tiles (side-effecting
//      DMA -> compiler CANNOT sink it past the spin; R4's register version
//      got de-pipelined: VGPR_Count=28 proved loads sunk to use sites)
//   2) poll-first: lane t<8 owns chunk base+t's pub words, s_sleep backoff
//   3) vmcnt(0) (drained during spin), ds_read_b64 + ballot accumulate
// XCD swizzle g=((b&7)<<3)|(b>>3): consecutive logical groups share an XCD L2.
// pub words self-flagged ((bits<<1)|1), relaxed atomics (data == flag).
// ---------------------------------------------------------------------------
__global__ __launch_bounds__(64, 1) void k_scan(const u64* __restrict__ mtile,
                                                u64* __restrict__ pub) {
  __shared__ u64 wA[8 * 64];
  __shared__ u64 wB[8 * 64];
  const int b = blockIdx.x;
  const int g = ((b & 7) << 3) | (b >> 3);
  const int r = threadIdx.x;
  const int ra = 2 * g, rb = 2 * g + 1;

  u64 dAA = mtile[((size_t)ra * NT + ra) * 64 + r];
  u64 dAB = mtile[((size_t)ra * NT + rb) * 64 + r];
  u64 dBB = mtile[((size_t)rb * NT + rb) * 64 + r];

  u64 acc0 = 0, acc1 = 0;       // removed-by-previous-heads bits (ballot space)
  const int kend = 2 * g;       // previous 64-col chunks

  for (int base = 0; base < kend; base += 8) {
    // 1) async prefetch: 8 chunks x 512B per row-tile, 16B/lane DMA to LDS.
    //    (base+7 <= 127 always: kend<=126 even, base<=120. Chunks >= kend get
    //    h=0 below, so prefetching them is harmless.)
    const u64* gA = mtile + ((size_t)ra * NT + base) * 64;
    const u64* gB = mtile + ((size_t)rb * NT + base) * 64;
#pragma unroll
    for (int q = 0; q < 4; ++q) {
      __builtin_amdgcn_global_load_lds((gas_void*)(gA + q * 128 + 2 * r),
                                       (las_void*)(&wA[q * 128]), 16, 0, 0);
      __builtin_amdgcn_global_load_lds((gas_void*)(gB + q * 128 + 2 * r),
                                       (las_void*)(&wB[q * 128]), 16, 0, 0);
    }
    // 2) poll this window's pubs: lane t<8 owns chunk base+t
    int k = base + r;
    bool need = (r < 8) && (k < kend);
    u64 w0 = 0, w1 = 0;
    for (;;) {
      if (need) {
        w0 = __hip_atomic_load(&pub[2 * k], __ATOMIC_RELAXED, __HIP_MEMORY_SCOPE_AGENT);
        w1 = __hip_atomic_load(&pub[2 * k + 1], __ATOMIC_RELAXED, __HIP_MEMORY_SCOPE_AGENT);
      }
      if (__ballot(!need || ((w0 & w1) & 1ull)) == ~0ull) break;
      __builtin_amdgcn_s_sleep(1);
    }
    u64 hv = (w0 >> 1) | ((w1 >> 1) << 32);   // 0 for !need lanes -> no-op chunks
    // 3) consume
    asm volatile("s_waitcnt vmcnt(0)" ::: "memory");
#pragma unroll
    for (int t = 0; t < 8; ++t) {
      u64 h = readlane64(hv, t);
      u64 tA = wA[t * 64 + r];
      u64 tB = wB[t * 64 + r];
      acc0 |= __ballot((tA & h) != 0ull);
      acc1 |= __ballot((tB & h) != 0ull);
    }
  }

  // in-group greedy resolve (uniform scalar loop; self-bit adj[i][i]=1 clears i)
  u64 todo0 = ~acc0, todo1 = ~acc1;
  u64 hm0 = 0, hm1 = 0;
  while (todo0) {
    int i = __builtin_ctzll(todo0);
    hm0 |= 1ull << i;
    todo0 &= ~readlane64(dAA, i);
    todo1 &= ~readlane64(dAB, i);
  }
  while (todo1) {
    int i = __builtin_ctzll(todo1);
    hm1 |= 1ull << i;
    todo1 &= ~readlane64(dBB, i);
  }
  // publish: 4 words from 4 lanes
  u64 w = (r == 0) ? (((hm0 & 0xffffffffull) << 1) | 1ull)
        : (r == 1) ? (((hm0 >> 32) << 1) | 1ull)
        : (r == 2) ? (((hm1 & 0xffffffffull) << 1) | 1ull)
                   : (((hm1 >> 32) << 1) | 1ull);
  if (r < 4)
    __hip_atomic_store(&pub[4 * g + r], w, __ATOMIC_RELAXED, __HIP_MEMORY_SCOPE_AGENT);
}

// ---------------------------------------------------------------------------
// K6: parallel cluster assignment + segment atomics. Block per 64-row group;
// wave w scans col-chunks [32w,32w+32) coalesced; cluster[j] = first head
// adjacent to j (symmetry: row j == column j). Every j hits (itself if head).
// ---------------------------------------------------------------------------
__global__ __launch_bounds__(256) void k_cluster(const u64* __restrict__ mtile,
                                                 const u64* __restrict__ pub,
                                                 const float* __restrict__ ss,
                                                 const float* __restrict__ by2s,
                                                 int* __restrict__ cluster,
                                                 int* __restrict__ cnt,
                                                 float* __restrict__ prob,
                                                 unsigned* __restrict__ y2m) {
  __shared__ u64 hlds[NT];
  __shared__ int red[4][64];
  int gy = blockIdx.x;
  if (threadIdx.x < NT) {
    u64 plo = pub[2 * threadIdx.x], phi = pub[2 * threadIdx.x + 1];
    hlds[threadIdx.x] = (plo >> 1) | ((phi >> 1) << 32);
  }
  __syncthreads();
  int w = threadIdx.x >> 6, r = threadIdx.x & 63;
  int best = 0x7fffffff;
  for (int kk = 0; kk < 32; ++kk) {
    int k = 32 * w + kk;
    u64 v = mtile[((size_t)gy * NT + k) * 64 + r] & hlds[k];
    if (v && best == 0x7fffffff) best = k * 64 + __builtin_ctzll(v);
  }
  red[w][r] = best;
  __syncthreads();
  if (w == 0) {
    int b = min(min(red[0][r], red[1][r]), min(red[2][r], red[3][r]));
    int j = gy * 64 + r;
    cluster[j] = b;
    atomicAdd(&cnt[b], 1);
    atomicAdd(&prob[b], ss[j]);
    atomicMax(&y2m[b], __float_as_uint(by2s[j]));
  }
}

// ---------------------------------------------------------------------------
// K7: first index achieving the cluster max y2
// ---------------------------------------------------------------------------
__global__ __launch_bounds__(256) void k_first(const int* __restrict__ cluster,
                                               const float* __restrict__ by2s,
                                               const unsigned* __restrict__ y2m,
                                               int* __restrict__ first) {
  int j = blockIdx.x * 256 + threadIdx.x;
  if (j >= N) return;
  int c = cluster[j];
  if (by2s[j] >= __uint_as_float(y2m[c])) atomicMin(&first[c], j);
}

// ---------------------------------------------------------------------------
// K8: outputs. out[j][0..4] then keep[j] appended (floats 0/1).
// ---------------------------------------------------------------------------
__global__ __launch_bounds__(256) void k_out(const int* __restrict__ cluster,
                                             const float* __restrict__ bx1s, const float* __restrict__ by1s,
                                             const float* __restrict__ bx2s, const float* __restrict__ by2s,
                                             const int* __restrict__ cnt,
                                             const float* __restrict__ prob,
                                             const int* __restrict__ first,
                                             const int* __restrict__ num_models,
                                             float* __restrict__ out) {
  int j = blockIdx.x * 256 + threadIdx.x;
  if (j >= N) return;
  int c = cluster[j];
  int nm = num_models[0];
  bool valid = (float)cnt[c] >= (float)nm / 3.0f;
  bool pick = (first[c] == j);
  bool keep = pick && valid;
  float o0 = 0.f, o1 = 0.f, o2 = 0.f, o3 = 0.f, o4 = 0.f;
  if (keep) {
    o0 = bx1s[j]; o1 = by1s[j]; o2 = bx2s[j]; o3 = by2s[j];
    o4 = prob[c] / (float)nm;
  }
  out[j * 5 + 0] = o0;
  out[j * 5 + 1] = o1;
  out[j * 5 + 2] = o2;
  out[j * 5 + 3] = o3;
  out[j * 5 + 4] = o4;
  out[N * 5 + j] = keep ? 1.0f : 0.0f;
}

// ---------------------------------------------------------------------------
extern "C" void kernel_launch(void* const* d_in, const int* in_sizes, int n_in,
                              void* d_out, int out_size, void* d_ws, size_t ws_size,
                              hipStream_t stream) {
  const float* boxes = (const float*)d_in[0];
  const float* scores = (const float*)d_in[1];
  const int* num_models = (const int*)d_in[2];
  float* out = (float*)d_out;

  char* p = (char*)d_ws;
  auto take = [&](size_t bytes) {
    char* r = p;
    p += (bytes + 255) & ~(size_t)255;
    return r;
  };
  u64* keys   = (u64*)take((size_t)N * 8);
  int* rank   = (int*)take((size_t)N * 4);
  float* bx1s = (float*)take((size_t)N * 4);
  float* by1s = (float*)take((size_t)N * 4);
  float* bx2s = (float*)take((size_t)N * 4);
  float* by2s = (float*)take((size_t)N * 4);
  float* ss   = (float*)take((size_t)N * 4);
  float* areas= (float*)take((size_t)N * 4);
  int* cluster= (int*)take((size_t)N * 4);
  int* cnt    = (int*)take((size_t)N * 4);
  float* prob = (float*)take((size_t)N * 4);
  unsigned* y2m = (unsigned*)take((size_t)N * 4);
  int* first  = (int*)take((size_t)N * 4);
  u64* pub    = (u64*)take((size_t)2 * NT * 8);      // 256 publish words
  u64* mtile  = (u64*)take((size_t)NT * NT * 64 * 8); // 8 MiB tiled adjacency

  k_init<<<N / 256, 256, 0, stream>>>(scores, keys, rank, cnt, prob, y2m, first, pub);
  k_rank<<<dim3(N / 256, 8), 256, 0, stream>>>(keys, rank);
  k_scatter<<<N / 256, 256, 0, stream>>>(boxes, scores, rank, bx1s, by1s, bx2s, by2s, ss, areas);
  k_adj<<<dim3(NT, NT), 64, 0, stream>>>(bx1s, by1s, bx2s, by2s, areas, mtile);
  k_scan<<<NGRP, 64, 0, stream>>>(mtile, pub);
  k_cluster<<<N / 64, 256, 0, stream>>>(mtile, pub, ss, by2s, cluster, cnt, prob, y2m);
  k_first<<<N / 256, 256, 0, stream>>>(cluster, by2s, y2m, first);
  k_out<<<N / 256, 256, 0, stream>>>(cluster, bx1s, by1s, bx2s, by2s, cnt, prob, first, num_models, out);
}